// Round 2
// baseline (1500.602 us; speedup 1.0000x reference)
//
#include <hip/hip_runtime.h>

// Problem constants (from reference)
#define BSAMP 4096
#define NTOT  65536
#define CHUNK 16384
#define INW   64
#define HW    512
#define DW    256
#define EMB_IN 832   // INW + HW + DW

using bf16x8 = __attribute__((ext_vector_type(8))) short;
using f32x4  = __attribute__((ext_vector_type(4))) float;

__device__ __forceinline__ unsigned short f2bf(float f) {
    unsigned int x = __builtin_bit_cast(unsigned int, f);
    x = x + 0x7fff + ((x >> 16) & 1);   // round-to-nearest-even
    return (unsigned short)(x >> 16);
}

// ---------------------------------------------------------------------------
// generic fp32 -> bf16 convert
__global__ __launch_bounds__(256) void k_cvt(const float* __restrict__ in,
                                             unsigned short* __restrict__ out, int n) {
    int i = blockIdx.x * 256 + threadIdx.x;
    if (i < n) out[i] = f2bf(in[i]);
}

// transpose + convert: W_emb fp32 [832][512] -> wembT bf16 [512][832]
__global__ __launch_bounds__(256) void k_transpose(const float* __restrict__ in,
                                                   unsigned short* __restrict__ out) {
    int i = blockIdx.x * 256 + threadIdx.x;
    if (i >= HW * EMB_IN) return;
    int n = i / EMB_IN;
    int k = i - n * EMB_IN;
    out[i] = f2bf(in[k * HW + n]);
}

// sample id per neighbor row (upper_bound over starts, -1)
__global__ __launch_bounds__(256) void k_sid(const int* __restrict__ starts,
                                             int* __restrict__ sid) {
    int n = blockIdx.x * 256 + threadIdx.x;
    int lo = 0, hi = BSAMP - 1;
    #pragma unroll
    for (int it = 0; it < 12; ++it) {       // ceil(log2(4096)) = 12
        int mid = (lo + hi + 1) >> 1;
        if (starts[mid] <= n) lo = mid; else hi = mid - 1;
    }
    sid[n] = lo;
}

// ---------------------------------------------------------------------------
// emb = relu(concat(neighbor_t, traj[sid], dist) @ W_emb + b_emb), bf16 out.
// One chunk of 16384 rows. Block tile 128x128, 4 waves (2x2) of 64x64.
__global__ __launch_bounds__(256) void k_emb(const float* __restrict__ neigh,
                                             const unsigned short* __restrict__ trajbf,
                                             const float* __restrict__ dist,
                                             const unsigned short* __restrict__ wembT,
                                             const float* __restrict__ bemb,
                                             const int* __restrict__ sid,
                                             unsigned short* __restrict__ emb,
                                             int row_base) {
    __shared__ short As[128 * 64];
    __shared__ short Bs[128 * 64];
    __shared__ int sid_s[128];

    const int tid  = threadIdx.x;
    const int rb   = blockIdx.y;           // 0..127
    const int cb   = blockIdx.x;           // 0..3
    const int row0 = row_base + rb * 128;  // global row
    const int lrow0 = rb * 128;            // chunk-local row

    if (tid < 128) sid_s[tid] = sid[row0 + tid];

    f32x4 acc[4][4];
    #pragma unroll
    for (int i = 0; i < 4; ++i)
        #pragma unroll
        for (int j = 0; j < 4; ++j) acc[i][j] = (f32x4){0.f, 0.f, 0.f, 0.f};

    const int wave = tid >> 6, lane = tid & 63;
    const int wm = wave & 1, wn = wave >> 1;
    const int quad = lane >> 4, l15 = lane & 15;
    const int mb = wm * 64, nb = wn * 64;

    __syncthreads();

    for (int kk = 0; kk < 13; ++kk) {
        // ---- stage A tile: 128 rows x 64 k ----
        if (kk == 0) {
            // neighbor_t fp32, cols 0..63
            #pragma unroll
            for (int p = 0; p < 8; ++p) {
                int idx = p * 256 + tid;
                int row = idx >> 4, c4 = idx & 15;
                float4 v = *(const float4*)(neigh + (row0 + row) * INW + c4 * 4);
                unsigned short* d = (unsigned short*)&As[row * 64 + c4 * 4];
                d[0] = f2bf(v.x); d[1] = f2bf(v.y); d[2] = f2bf(v.z); d[3] = f2bf(v.w);
            }
        } else if (kk <= 8) {
            // traj (pre-converted bf16), gathered
            #pragma unroll
            for (int p = 0; p < 4; ++p) {
                int idx = p * 256 + tid;
                int row = idx >> 3, c8 = idx & 7;
                *(float4*)(&As[row * 64 + c8 * 8]) =
                    *(const float4*)(trajbf + sid_s[row] * HW + (kk - 1) * 64 + c8 * 8);
            }
        } else {
            // dist fp32
            #pragma unroll
            for (int p = 0; p < 8; ++p) {
                int idx = p * 256 + tid;
                int row = idx >> 4, c4 = idx & 15;
                float4 v = *(const float4*)(dist + (row0 + row) * DW + (kk - 9) * 64 + c4 * 4);
                unsigned short* d = (unsigned short*)&As[row * 64 + c4 * 4];
                d[0] = f2bf(v.x); d[1] = f2bf(v.y); d[2] = f2bf(v.z); d[3] = f2bf(v.w);
            }
        }
        // ---- stage B tile: wembT rows [cb*128,+128), cols [kk*64,+64) ----
        #pragma unroll
        for (int p = 0; p < 4; ++p) {
            int idx = p * 256 + tid;
            int row = idx >> 3, c8 = idx & 7;
            *(float4*)(&Bs[row * 64 + c8 * 8]) =
                *(const float4*)(wembT + (cb * 128 + row) * EMB_IN + kk * 64 + c8 * 8);
        }
        __syncthreads();

        #pragma unroll
        for (int ks = 0; ks < 2; ++ks) {
            bf16x8 af[4], bfr[4];
            #pragma unroll
            for (int i = 0; i < 4; ++i)
                af[i] = *(const bf16x8*)(&As[(mb + i * 16 + l15) * 64 + ks * 32 + quad * 8]);
            #pragma unroll
            for (int j = 0; j < 4; ++j)
                bfr[j] = *(const bf16x8*)(&Bs[(nb + j * 16 + l15) * 64 + ks * 32 + quad * 8]);
            #pragma unroll
            for (int i = 0; i < 4; ++i)
                #pragma unroll
                for (int j = 0; j < 4; ++j)
                    acc[i][j] = __builtin_amdgcn_mfma_f32_16x16x32_bf16(af[i], bfr[j], acc[i][j], 0, 0, 0);
        }
        __syncthreads();
    }

    // epilogue: bias + relu, store bf16 (chunk-local)
    #pragma unroll
    for (int j = 0; j < 4; ++j) {
        int gn = cb * 128 + nb + j * 16 + l15;
        float bias = bemb[gn];
        #pragma unroll
        for (int i = 0; i < 4; ++i) {
            int lm0 = lrow0 + mb + i * 16 + quad * 4;
            #pragma unroll
            for (int r = 0; r < 4; ++r) {
                float v = acc[i][j][r] + bias;
                v = v > 0.f ? v : 0.f;
                emb[(lm0 + r) * HW + gn] = f2bf(v);
            }
        }
    }
}

// ---------------------------------------------------------------------------
// fused GRUCell for one chunk. Block = 64 rows x 64 h-cols of the output.
__global__ __launch_bounds__(256) void k_gru(const unsigned short* __restrict__ emb,
                                             const float* __restrict__ ht,
                                             const unsigned short* __restrict__ wihT,
                                             const unsigned short* __restrict__ whhT,
                                             const float* __restrict__ bih,
                                             const float* __restrict__ bhh,
                                             float* __restrict__ out,
                                             int row_base) {
    __shared__ short As[64 * 64];
    __shared__ short Bs[3 * 64 * 64];

    const int tid  = threadIdx.x;
    const int rb   = blockIdx.y;          // 0..255
    const int hb   = blockIdx.x;          // 0..7
    const int lrow0 = rb * 64;            // chunk-local
    const int row0  = row_base + lrow0;   // global
    const int h0    = hb * 64;

    const int wave = tid >> 6, lane = tid & 63;
    const int wm = wave & 1, wn = wave >> 1;
    const int quad = lane >> 4, l15 = lane & 15;
    const int mb = wm * 32, nb = wn * 32;

    f32x4 accI[3][2][2], accH[3][2][2];
    #pragma unroll
    for (int g = 0; g < 3; ++g)
        #pragma unroll
        for (int i = 0; i < 2; ++i)
            #pragma unroll
            for (int j = 0; j < 2; ++j) {
                accI[g][i][j] = (f32x4){0.f, 0.f, 0.f, 0.f};
                accH[g][i][j] = (f32x4){0.f, 0.f, 0.f, 0.f};
            }

    for (int phase = 0; phase < 2; ++phase) {
        const unsigned short* W = phase ? whhT : wihT;

        for (int kk = 0; kk < 8; ++kk) {
            // ---- stage A: 64 rows x 64 k ----
            if (phase == 0) {
                // emb, bf16 chunk-local
                #pragma unroll
                for (int p = 0; p < 2; ++p) {
                    int idx = p * 256 + tid;
                    int row = idx >> 3, c8 = idx & 7;
                    *(float4*)(&As[row * 64 + c8 * 8]) =
                        *(const float4*)(emb + (lrow0 + row) * HW + kk * 64 + c8 * 8);
                }
            } else {
                // ht fp32 global
                #pragma unroll
                for (int p = 0; p < 4; ++p) {
                    int idx = p * 256 + tid;
                    int row = idx >> 4, c4 = idx & 15;
                    float4 v = *(const float4*)(ht + (row0 + row) * HW + kk * 64 + c4 * 4);
                    unsigned short* d = (unsigned short*)&As[row * 64 + c4 * 4];
                    d[0] = f2bf(v.x); d[1] = f2bf(v.y); d[2] = f2bf(v.z); d[3] = f2bf(v.w);
                }
            }
            // ---- stage B: 3 gate row-groups of W (bf16, already B^T layout) ----
            #pragma unroll
            for (int g = 0; g < 3; ++g)
                #pragma unroll
                for (int p = 0; p < 2; ++p) {
                    int idx = p * 256 + tid;
                    int row = idx >> 3, c8 = idx & 7;
                    *(float4*)(&Bs[g * 4096 + row * 64 + c8 * 8]) =
                        *(const float4*)(W + (g * HW + h0 + row) * HW + kk * 64 + c8 * 8);
                }
            __syncthreads();

            f32x4 (*acc)[2][2] = phase ? accH : accI;
            #pragma unroll
            for (int ks = 0; ks < 2; ++ks) {
                bf16x8 af[2];
                #pragma unroll
                for (int i = 0; i < 2; ++i)
                    af[i] = *(const bf16x8*)(&As[(mb + i * 16 + l15) * 64 + ks * 32 + quad * 8]);
                #pragma unroll
                for (int g = 0; g < 3; ++g) {
                    bf16x8 b0 = *(const bf16x8*)(&Bs[g * 4096 + (nb + l15) * 64 + ks * 32 + quad * 8]);
                    bf16x8 b1 = *(const bf16x8*)(&Bs[g * 4096 + (nb + 16 + l15) * 64 + ks * 32 + quad * 8]);
                    #pragma unroll
                    for (int i = 0; i < 2; ++i) {
                        acc[g][i][0] = __builtin_amdgcn_mfma_f32_16x16x32_bf16(af[i], b0, acc[g][i][0], 0, 0, 0);
                        acc[g][i][1] = __builtin_amdgcn_mfma_f32_16x16x32_bf16(af[i], b1, acc[g][i][1], 0, 0, 0);
                    }
                }
            }
            __syncthreads();
        }
    }

    // epilogue: gates + output (fp32)
    #pragma unroll
    for (int j = 0; j < 2; ++j) {
        int gn = h0 + nb + j * 16 + l15;
        float bir = bih[gn],        bhr = bhh[gn];
        float biz = bih[gn + 512],  bhz = bhh[gn + 512];
        float bin = bih[gn + 1024], bhn = bhh[gn + 1024];
        #pragma unroll
        for (int i = 0; i < 2; ++i) {
            int gm0 = row0 + mb + i * 16 + quad * 4;
            #pragma unroll
            for (int r = 0; r < 4; ++r) {
                int gm = gm0 + r;
                float ir = accI[0][i][j][r] + bir, hr = accH[0][i][j][r] + bhr;
                float iz = accI[1][i][j][r] + biz, hz = accH[1][i][j][r] + bhz;
                float inn = accI[2][i][j][r] + bin, hn = accH[2][i][j][r] + bhn;
                float rg = 1.f / (1.f + __expf(-(ir + hr)));
                float zg = 1.f / (1.f + __expf(-(iz + hz)));
                float ng = tanhf(inn + rg * hn);
                float hp = ht[gm * HW + gn];
                out[gm * HW + gn] = (1.f - zg) * ng + zg * hp;
            }
        }
    }
}

// ---------------------------------------------------------------------------
extern "C" void kernel_launch(void* const* d_in, const int* in_sizes, int n_in,
                              void* d_out, int out_size, void* d_ws, size_t ws_size,
                              hipStream_t stream) {
    const float* traj   = (const float*)d_in[0];
    const float* neigh  = (const float*)d_in[1];
    const float* dist   = (const float*)d_in[2];
    const float* ht     = (const float*)d_in[3];
    const float* W_emb  = (const float*)d_in[4];
    const float* b_emb  = (const float*)d_in[5];
    const float* w_ih   = (const float*)d_in[6];
    const float* w_hh   = (const float*)d_in[7];
    const float* b_ih   = (const float*)d_in[8];
    const float* b_hh   = (const float*)d_in[9];
    const int*   starts = (const int*)d_in[10];

    // workspace layout (bytes)
    char* ws = (char*)d_ws;
    int*            sid    = (int*)ws;                               //   0 .. 256K
    unsigned short* wembT  = (unsigned short*)(ws + 262144);         // 832K  (512*832*2)
    unsigned short* wihT   = (unsigned short*)(ws + 1114112);        // 1.5M  (1536*512*2)
    unsigned short* whhT   = (unsigned short*)(ws + 2686976);        // 1.5M
    unsigned short* trajbf = (unsigned short*)(ws + 4259840);        // 4M    (4096*512*2)
    unsigned short* emb    = (unsigned short*)(ws + 8454144);        // 16M   (16384*512*2)

    float* out = (float*)d_out;

    k_cvt<<<dim3((1536 * 512 + 255) / 256), dim3(256), 0, stream>>>(w_ih, wihT, 1536 * 512);
    k_cvt<<<dim3((1536 * 512 + 255) / 256), dim3(256), 0, stream>>>(w_hh, whhT, 1536 * 512);
    k_cvt<<<dim3((BSAMP * HW + 255) / 256), dim3(256), 0, stream>>>(traj, trajbf, BSAMP * HW);
    k_transpose<<<dim3((HW * EMB_IN + 255) / 256), dim3(256), 0, stream>>>(W_emb, wembT);
    k_sid<<<dim3(NTOT / 256), dim3(256), 0, stream>>>(starts, sid);

    for (int c = 0; c < NTOT / CHUNK; ++c) {
        int base = c * CHUNK;
        k_emb<<<dim3(4, CHUNK / 128), dim3(256), 0, stream>>>(neigh, trajbf, dist, wembT,
                                                              b_emb, sid, emb, base);
        k_gru<<<dim3(8, CHUNK / 64), dim3(256), 0, stream>>>(emb, ht, wihT, whhT,
                                                             b_ih, b_hh, out, base);
    }
}

// Round 3
// 810.174 us; speedup vs baseline: 1.8522x; 1.8522x over previous
//
#include <hip/hip_runtime.h>
#include <stdint.h>

#define BSAMP 4096
#define NTOT  65536
#define INW   64
#define HW    512
#define DW    256
#define EMB_IN 832

typedef unsigned short ushort_t;
using bf16x8 = __attribute__((ext_vector_type(8))) short;
using f32x4  = __attribute__((ext_vector_type(4))) float;

__device__ __forceinline__ ushort_t f2bf(float f) {
    unsigned int x = __builtin_bit_cast(unsigned int, f);
    x = x + 0x7fff + ((x >> 16) & 1);   // round-to-nearest-even
    return (ushort_t)(x >> 16);
}

// async global->LDS, 16B per lane; lds base must be wave-uniform (HW scatters +lane*16)
__device__ __forceinline__ void async16(const void* g, void* l) {
    __builtin_amdgcn_global_load_lds((const __attribute__((address_space(1))) unsigned int*)g,
                                     (__attribute__((address_space(3))) unsigned int*)l,
                                     16, 0, 0);
}

// ---------------------------------------------------------------------------
__global__ __launch_bounds__(256) void k_cvt(const float* __restrict__ in,
                                             ushort_t* __restrict__ out, int n) {
    int i = blockIdx.x * 256 + threadIdx.x;
    if (i < n) out[i] = f2bf(in[i]);
}

// W_emb fp32 [832][512] -> wembT bf16 [512][832]
__global__ __launch_bounds__(256) void k_transpose(const float* __restrict__ in,
                                                   ushort_t* __restrict__ out) {
    int i = blockIdx.x * 256 + threadIdx.x;
    if (i >= HW * EMB_IN) return;
    int n = i / EMB_IN;
    int k = i - n * EMB_IN;
    out[i] = f2bf(in[k * HW + n]);
}

// wrz[g*512+h][k] = k<512 ? w_ih[(g*512+h)][k] : w_hh[(g*512+h)][k-512],  g in {r,z}
__global__ __launch_bounds__(256) void k_build_wrz(const float* __restrict__ wih,
                                                   const float* __restrict__ whh,
                                                   ushort_t* __restrict__ wrz) {
    int i = blockIdx.x * 256 + threadIdx.x;           // 1024*1024
    int row = i >> 10, k = i & 1023;
    float v = (k < 512) ? wih[row * 512 + k] : whh[row * 512 + (k - 512)];
    wrz[i] = f2bf(v);
}

// wnn[h][k] = k<512 ? w_ih[1024+h][k] : w_hh[1024+h][k-512]
__global__ __launch_bounds__(256) void k_build_wnn(const float* __restrict__ wih,
                                                   const float* __restrict__ whh,
                                                   ushort_t* __restrict__ wnn) {
    int i = blockIdx.x * 256 + threadIdx.x;           // 512*1024
    int h = i >> 10, k = i & 1023;
    float v = (k < 512) ? wih[(1024 + h) * 512 + k] : whh[(1024 + h) * 512 + (k - 512)];
    wnn[i] = f2bf(v);
}

__global__ __launch_bounds__(256) void k_sid(const int* __restrict__ starts,
                                             int* __restrict__ sid) {
    int n = blockIdx.x * 256 + threadIdx.x;
    int lo = 0, hi = BSAMP - 1;
    #pragma unroll
    for (int it = 0; it < 12; ++it) {
        int mid = (lo + hi + 1) >> 1;
        if (starts[mid] <= n) lo = mid; else hi = mid - 1;
    }
    sid[n] = lo;
}

// ht (chunk, fp32, pre-offset) -> Acat cols 512..1023 bf16
__global__ __launch_bounds__(256) void k_cvt_ht(const float* __restrict__ ht,
                                                ushort_t* __restrict__ Acat, int n128) {
    int i = blockIdx.x * 256 + threadIdx.x;           // nrows*128
    if (i >= n128) return;
    int row = i >> 7, c4 = i & 127;
    float4 v = *(const float4*)(ht + row * 512 + c4 * 4);
    ushort_t* d = Acat + (size_t)row * 1024 + 512 + c4 * 4;
    d[0] = f2bf(v.x); d[1] = f2bf(v.y); d[2] = f2bf(v.z); d[3] = f2bf(v.w);
}

// ---------------------------------------------------------------------------
// emb = relu(concat(neigh, traj[sid], dist) @ W_emb + b) -> Acat cols 0..511 (bf16)
// 128x128 tile, 4 waves (2x2) of 64x64, BK=64, K=832.
__global__ __launch_bounds__(256) void k_emb(const float* __restrict__ neigh,
                                             const ushort_t* __restrict__ trajbf,
                                             const float* __restrict__ dist,
                                             const ushort_t* __restrict__ wembT,
                                             const float* __restrict__ bemb,
                                             const int* __restrict__ sid,
                                             ushort_t* __restrict__ Acat,
                                             int base) {
    __shared__ short As[128 * 64];
    __shared__ short Bs[128 * 64];

    const int tid = threadIdx.x;
    const int cb = blockIdx.x, rb = blockIdx.y;
    const int lrow0 = rb * 128;
    const int row0g = base + lrow0;
    const int wave = tid >> 6, lane = tid & 63;
    const int wm = wave & 1, wn = wave >> 1;
    const int quad = lane >> 4, l15 = lane & 15;
    const int mb = wm * 64, nb = wn * 64;
    const int srow = lane >> 3, sc8 = lane & 7;

    f32x4 acc[4][4];
    #pragma unroll
    for (int i = 0; i < 4; ++i)
        #pragma unroll
        for (int j = 0; j < 4; ++j) acc[i][j] = (f32x4){0.f, 0.f, 0.f, 0.f};

    for (int kk = 0; kk < 13; ++kk) {
        // ---- B tile: wembT rows [cb*128,+128), cols [kk*64,+64) — async ----
        #pragma unroll
        for (int p = 0; p < 4; ++p) {
            int row = p * 32 + wave * 8 + srow;
            async16(wembT + (cb * 128 + row) * EMB_IN + kk * 64 + sc8 * 8,
                    &Bs[p * 2048 + wave * 512]);
        }
        // ---- A tile: 128 x 64 ----
        if (kk == 0) {                       // neigh fp32
            #pragma unroll
            for (int p = 0; p < 8; ++p) {
                int idx = p * 256 + tid;
                int row = idx >> 4, c4 = idx & 15;
                float4 v = *(const float4*)(neigh + (row0g + row) * INW + c4 * 4);
                ushort_t* d = (ushort_t*)&As[row * 64 + c4 * 4];
                d[0] = f2bf(v.x); d[1] = f2bf(v.y); d[2] = f2bf(v.z); d[3] = f2bf(v.w);
            }
        } else if (kk <= 8) {                // traj gather, bf16 async
            #pragma unroll
            for (int p = 0; p < 4; ++p) {
                int row = p * 32 + wave * 8 + srow;
                int s = sid[row0g + row];
                async16(trajbf + s * HW + (kk - 1) * 64 + sc8 * 8,
                        &As[p * 2048 + wave * 512]);
            }
        } else {                             // dist fp32
            #pragma unroll
            for (int p = 0; p < 8; ++p) {
                int idx = p * 256 + tid;
                int row = idx >> 4, c4 = idx & 15;
                float4 v = *(const float4*)(dist + (row0g + row) * DW + (kk - 9) * 64 + c4 * 4);
                ushort_t* d = (ushort_t*)&As[row * 64 + c4 * 4];
                d[0] = f2bf(v.x); d[1] = f2bf(v.y); d[2] = f2bf(v.z); d[3] = f2bf(v.w);
            }
        }
        __syncthreads();

        #pragma unroll
        for (int ks = 0; ks < 2; ++ks) {
            const int kb = ks * 32 + quad * 8;
            bf16x8 af[4], bfr[4];
            #pragma unroll
            for (int i = 0; i < 4; ++i)
                af[i] = *(const bf16x8*)(&As[(mb + i * 16 + l15) * 64 + kb]);
            #pragma unroll
            for (int j = 0; j < 4; ++j)
                bfr[j] = *(const bf16x8*)(&Bs[(nb + j * 16 + l15) * 64 + kb]);
            #pragma unroll
            for (int i = 0; i < 4; ++i)
                #pragma unroll
                for (int j = 0; j < 4; ++j)
                    acc[i][j] = __builtin_amdgcn_mfma_f32_16x16x32_bf16(af[i], bfr[j], acc[i][j], 0, 0, 0);
        }
        __syncthreads();
    }

    // epilogue: bias + relu -> Acat cols 0..511 (stride 1024)
    #pragma unroll
    for (int j = 0; j < 4; ++j) {
        int gn = cb * 128 + nb + j * 16 + l15;
        float bias = bemb[gn];
        #pragma unroll
        for (int i = 0; i < 4; ++i) {
            int lm0 = lrow0 + mb + i * 16 + quad * 4;
            #pragma unroll
            for (int r = 0; r < 4; ++r) {
                float v = acc[i][j][r] + bias;
                v = v > 0.f ? v : 0.f;
                Acat[(size_t)(lm0 + r) * 1024 + gn] = f2bf(v);
            }
        }
    }
}

// ---------------------------------------------------------------------------
// fused GRU: block = 128 rows x 64 h-cols; waves 2x2, wave = 64x32.
// acc tiles: r,z (K=1024 fused), n_i (kk<8), n_h (kk>=8).
__global__ __launch_bounds__(256, 2) void k_gru(const ushort_t* __restrict__ Acat,
                                                const float* __restrict__ ht,
                                                const ushort_t* __restrict__ wrz,
                                                const ushort_t* __restrict__ wnn,
                                                const float* __restrict__ bih,
                                                const float* __restrict__ bhh,
                                                float* __restrict__ out,
                                                int base) {
    __shared__ short As[128 * 64];
    __shared__ short Bs[3 * 64 * 64];

    const int tid = threadIdx.x;
    const int hb = blockIdx.x, rb = blockIdx.y;
    const int lrow0 = rb * 128;
    const int row0g = base + lrow0;
    const int h0 = hb * 64;
    const int wave = tid >> 6, lane = tid & 63;
    const int wm = wave & 1, wn = wave >> 1;
    const int quad = lane >> 4, l15 = lane & 15;
    const int mb = wm * 64, nb = wn * 32;
    const int srow = lane >> 3, sc8 = lane & 7;

    f32x4 accR[4][2], accZ[4][2], accNI[4][2], accNH[4][2];
    #pragma unroll
    for (int i = 0; i < 4; ++i)
        #pragma unroll
        for (int j = 0; j < 2; ++j) {
            accR[i][j] = (f32x4){0.f, 0.f, 0.f, 0.f};
            accZ[i][j] = (f32x4){0.f, 0.f, 0.f, 0.f};
            accNI[i][j] = (f32x4){0.f, 0.f, 0.f, 0.f};
            accNH[i][j] = (f32x4){0.f, 0.f, 0.f, 0.f};
        }

    const ushort_t* Wr = wrz + (size_t)h0 * 1024;
    const ushort_t* Wz = wrz + (size_t)(512 + h0) * 1024;
    const ushort_t* Wn = wnn + (size_t)h0 * 1024;

    auto body = [&](int kk, f32x4 (&accN)[4][2]) {
        // A: Acat rows [lrow0,+128), cols [kk*64,+64) — 4 async passes
        #pragma unroll
        for (int p = 0; p < 4; ++p) {
            int row = p * 32 + wave * 8 + srow;
            async16(Acat + (size_t)(lrow0 + row) * 1024 + kk * 64 + sc8 * 8,
                    &As[p * 2048 + wave * 512]);
        }
        // B: three 64x64 tiles (r, z, n-part) — 2 async passes each
        #pragma unroll
        for (int p = 0; p < 2; ++p) {
            int row = p * 32 + wave * 8 + srow;
            int goff = row * 1024 + kk * 64 + sc8 * 8;
            int loff = p * 2048 + wave * 512;
            async16(Wr + goff, &Bs[loff]);
            async16(Wz + goff, &Bs[4096 + loff]);
            async16(Wn + goff, &Bs[8192 + loff]);
        }
        __syncthreads();

        #pragma unroll
        for (int ks = 0; ks < 2; ++ks) {
            const int kb = ks * 32 + quad * 8;
            bf16x8 af[4];
            #pragma unroll
            for (int i = 0; i < 4; ++i)
                af[i] = *(const bf16x8*)(&As[(mb + i * 16 + l15) * 64 + kb]);

            bf16x8 br0 = *(const bf16x8*)(&Bs[(nb + l15) * 64 + kb]);
            bf16x8 br1 = *(const bf16x8*)(&Bs[(nb + 16 + l15) * 64 + kb]);
            #pragma unroll
            for (int i = 0; i < 4; ++i) {
                accR[i][0] = __builtin_amdgcn_mfma_f32_16x16x32_bf16(af[i], br0, accR[i][0], 0, 0, 0);
                accR[i][1] = __builtin_amdgcn_mfma_f32_16x16x32_bf16(af[i], br1, accR[i][1], 0, 0, 0);
            }
            bf16x8 bz0 = *(const bf16x8*)(&Bs[4096 + (nb + l15) * 64 + kb]);
            bf16x8 bz1 = *(const bf16x8*)(&Bs[4096 + (nb + 16 + l15) * 64 + kb]);
            #pragma unroll
            for (int i = 0; i < 4; ++i) {
                accZ[i][0] = __builtin_amdgcn_mfma_f32_16x16x32_bf16(af[i], bz0, accZ[i][0], 0, 0, 0);
                accZ[i][1] = __builtin_amdgcn_mfma_f32_16x16x32_bf16(af[i], bz1, accZ[i][1], 0, 0, 0);
            }
            bf16x8 bn0 = *(const bf16x8*)(&Bs[8192 + (nb + l15) * 64 + kb]);
            bf16x8 bn1 = *(const bf16x8*)(&Bs[8192 + (nb + 16 + l15) * 64 + kb]);
            #pragma unroll
            for (int i = 0; i < 4; ++i) {
                accN[i][0] = __builtin_amdgcn_mfma_f32_16x16x32_bf16(af[i], bn0, accN[i][0], 0, 0, 0);
                accN[i][1] = __builtin_amdgcn_mfma_f32_16x16x32_bf16(af[i], bn1, accN[i][1], 0, 0, 0);
            }
        }
        __syncthreads();
    };

    for (int kk = 0; kk < 8; ++kk)  body(kk, accNI);
    for (int kk = 8; kk < 16; ++kk) body(kk, accNH);

    // epilogue
    #pragma unroll
    for (int j = 0; j < 2; ++j) {
        int gn = h0 + nb + j * 16 + l15;
        float br = bih[gn] + bhh[gn];
        float bz = bih[gn + 512] + bhh[gn + 512];
        float bin = bih[gn + 1024], bhn = bhh[gn + 1024];
        #pragma unroll
        for (int i = 0; i < 4; ++i) {
            int gm0 = row0g + mb + i * 16 + quad * 4;
            #pragma unroll
            for (int r = 0; r < 4; ++r) {
                int gm = gm0 + r;
                float rg = 1.f / (1.f + __expf(-(accR[i][j][r] + br)));
                float zg = 1.f / (1.f + __expf(-(accZ[i][j][r] + bz)));
                float ng = tanhf(accNI[i][j][r] + bin + rg * (accNH[i][j][r] + bhn));
                float hp = ht[(size_t)gm * HW + gn];
                out[(size_t)gm * HW + gn] = (1.f - zg) * ng + zg * hp;
            }
        }
    }
}

// ---------------------------------------------------------------------------
extern "C" void kernel_launch(void* const* d_in, const int* in_sizes, int n_in,
                              void* d_out, int out_size, void* d_ws, size_t ws_size,
                              hipStream_t stream) {
    const float* traj   = (const float*)d_in[0];
    const float* neigh  = (const float*)d_in[1];
    const float* dist   = (const float*)d_in[2];
    const float* ht     = (const float*)d_in[3];
    const float* W_emb  = (const float*)d_in[4];
    const float* b_emb  = (const float*)d_in[5];
    const float* w_ih   = (const float*)d_in[6];
    const float* w_hh   = (const float*)d_in[7];
    const float* b_ih   = (const float*)d_in[8];
    const float* b_hh   = (const float*)d_in[9];
    const int*   starts = (const int*)d_in[10];

    // ws layout (all 16B-aligned)
    char* ws = (char*)d_ws;
    int*      sid    = (int*)ws;                         // 262144
    ushort_t* wembT  = (ushort_t*)(ws + 262144);         // 851968
    ushort_t* wrz    = (ushort_t*)(ws + 1114112);        // 2097152
    ushort_t* wnn    = (ushort_t*)(ws + 3211264);        // 1048576
    ushort_t* trajbf = (ushort_t*)(ws + 4259840);        // 4194304
    ushort_t* Acat   = (ushort_t*)(ws + 8454144);        // chunk_rows * 2048 B

    float* out = (float*)d_out;

    // adaptive chunk size from available workspace (deterministic per call)
    long long avail = (long long)ws_size - 8454144LL;
    int chunk_rows = (int)(avail / 2048);
    chunk_rows &= ~127;
    if (chunk_rows > NTOT) chunk_rows = NTOT;
    if (chunk_rows < 128) chunk_rows = 128;

    k_sid<<<dim3(NTOT / 256), dim3(256), 0, stream>>>(starts, sid);
    k_cvt<<<dim3((BSAMP * HW + 255) / 256), dim3(256), 0, stream>>>(traj, trajbf, BSAMP * HW);
    k_transpose<<<dim3((HW * EMB_IN + 255) / 256), dim3(256), 0, stream>>>(W_emb, wembT);
    k_build_wrz<<<dim3(1024 * 1024 / 256), dim3(256), 0, stream>>>(w_ih, w_hh, wrz);
    k_build_wnn<<<dim3(512 * 1024 / 256), dim3(256), 0, stream>>>(w_ih, w_hh, wnn);

    for (int base = 0; base < NTOT; base += chunk_rows) {
        int rows = NTOT - base;
        if (rows > chunk_rows) rows = chunk_rows;
        int n128 = rows * 128;
        k_cvt_ht<<<dim3((n128 + 255) / 256), dim3(256), 0, stream>>>(ht + (size_t)base * HW, Acat, n128);
        k_emb<<<dim3(4, rows / 128), dim3(256), 0, stream>>>(neigh, trajbf, dist, wembT,
                                                             b_emb, sid, Acat, base);
        k_gru<<<dim3(8, rows / 128), dim3(256), 0, stream>>>(Acat, ht, wrz, wnn,
                                                             b_ih, b_hh, out, base);
    }
}